// Round 18
// baseline (179.006 us; speedup 1.0000x reference)
//
#include <hip/hip_runtime.h>
#include <hip/hip_bf16.h>

typedef __attribute__((ext_vector_type(4))) float f32x4;
typedef _Float16 f16;
typedef __attribute__((ext_vector_type(8))) _Float16 f16x8;
typedef __attribute__((ext_vector_type(2))) __fp16 pk16x2;       // cvt_pkrtz native return
typedef __attribute__((ext_vector_type(2))) unsigned int uint2v; // permlane*_swap return / 8B store

#define S_LEN 2048
#define D_DIM 128
#define QBLK 256
#define KVBLK 64
#define NKV (S_LEN / KVBLK)
#define LOG2E 1.44269504088896340736f
#define EXP2(x) __builtin_amdgcn_exp2f(x)   // raw v_exp_f32 (log2 domain)

__device__ __forceinline__ unsigned cvtpk(float a, float b) {
    union { pk16x2 p; unsigned u; } v;
    v.p = __builtin_amdgcn_cvt_pkrtz(a, b);
    return v.u;
}

// reduce over the 4 hi-groups (lanes sharing lo) via permlane swaps (VALU).
__device__ __forceinline__ float hired_max(float x) {
    uint2v s = __builtin_amdgcn_permlane16_swap(__float_as_uint(x), __float_as_uint(x), false, false);
    float m = fmaxf(__uint_as_float(s.x), __uint_as_float(s.y));
    uint2v s2 = __builtin_amdgcn_permlane32_swap(__float_as_uint(m), __float_as_uint(m), false, false);
    return fmaxf(__uint_as_float(s2.x), __uint_as_float(s2.y));
}
__device__ __forceinline__ float hired_sum(float x) {
    uint2v s = __builtin_amdgcn_permlane16_swap(__float_as_uint(x), __float_as_uint(x), false, false);
    float m = __uint_as_float(s.x) + __uint_as_float(s.y);
    uint2v s2 = __builtin_amdgcn_permlane32_swap(__float_as_uint(m), __float_as_uint(m), false, false);
    return __uint_as_float(s2.x) + __uint_as_float(s2.y);
}

// softmax(x2 @ x3^T) @ x3 ; Q = x2, K = V = x3, no scale. fp16 MFMA path.
// Round-15 per-wave compute (4->8 waves x 32 q, in-reg P via permlane, log2e
// Q + exp2) with BLOCK-level changes: QBLK=256 (8 waves share one staging of
// each K/V tile: staging LDS writes + cvtpk + global fetch all halve) and
// K/V double-buffered (64 KB) -> ONE barrier per tile; pack+write overlaps
// the PV drain. REGISTER RULE (r6/9/14/16): never request >2 waves/SIMD;
// (512,2) keeps the 256-reg/wave cap. stg[4] (halved) -> ~170 total regs.
__global__ __launch_bounds__(512, 2) void attn_kernel(
    const float* __restrict__ Q, const float* __restrict__ KV,
    float* __restrict__ Out)
{
    // XCD-aware swizzle: 512 blocks % 8 == 0 -> bijective chunked map.
    unsigned b = blockIdx.x;
    unsigned cpx = gridDim.x >> 3;               // 64
    unsigned work = (b & 7u) * cpx + (b >> 3);
    unsigned head = work >> 3;                   // 64 heads
    unsigned qt = work & 7u;                     // 8 q-tiles per head

    const float* Qh = Q + (size_t)head * (S_LEN * D_DIM) + (size_t)qt * QBLK * D_DIM;
    const float* Kh = KV + (size_t)head * (S_LEN * D_DIM);
    float* Oh = Out + (size_t)head * (S_LEN * D_DIM) + (size_t)qt * QBLK * D_DIM;

    const int tid = threadIdx.x;
    const int wv = tid >> 6;        // 0..7
    const int lane = tid & 63;
    const int lo = lane & 15;
    const int hi = lane >> 4;

    // 2 x (16 + 16) = 64 KB
    __shared__ __align__(16) f16 Ksh[2][KVBLK * D_DIM];   // [buf][kv][d], swizzled
    __shared__ __align__(16) f16 Vsh[2][D_DIM * KVBLK];   // [buf][d][kv] transposed, swizzled

    // staging map: thread owns 4 rows x 4 cols (512 threads cover 64x128)
    const int srow = (tid >> 5) * 4;   // 0,4,..60
    const int scol = (tid & 31) * 4;   // 0,4,..124

    // ---- Q fragments x log2e: Q[wv*32 + t*16 + lo][kc*32 + hi*8 + j] ----
    f16x8 qf[2][4];
    #pragma unroll
    for (int t = 0; t < 2; ++t) {
        const float* qr = Qh + (wv * 32 + t * 16 + lo) * D_DIM + hi * 8;
        #pragma unroll
        for (int kc = 0; kc < 4; ++kc) {
            f32x4 a = *(const f32x4*)(qr + kc * 32);
            f32x4 c = *(const f32x4*)(qr + kc * 32 + 4);
            union { unsigned u[4]; f16x8 v; } q;
            q.u[0] = cvtpk(a[0] * LOG2E, a[1] * LOG2E);
            q.u[1] = cvtpk(a[2] * LOG2E, a[3] * LOG2E);
            q.u[2] = cvtpk(c[0] * LOG2E, c[1] * LOG2E);
            q.u[3] = cvtpk(c[2] * LOG2E, c[3] * LOG2E);
            qf[t][kc] = q.v;
        }
    }

    f32x4 oacc[2][8];
    #pragma unroll
    for (int t = 0; t < 2; ++t)
        #pragma unroll
        for (int n = 0; n < 8; ++n) oacc[t][n] = (f32x4){0.f, 0.f, 0.f, 0.f};
    float mr[2] = {-1e30f, -1e30f};   // log2-domain running max
    float lr[2] = {0.f, 0.f};

    f32x4 stg[4];

    #define STAGE_LOAD(KT) do {                                               \
        const float* p_ = Kh + (size_t)(KT) * KVBLK * D_DIM + (size_t)srow * D_DIM + scol; \
        _Pragma("unroll")                                                     \
        for (int i_ = 0; i_ < 4; ++i_) stg[i_] = *(const f32x4*)(p_ + i_ * D_DIM); \
    } while (0)

    #define STAGE_WRITE(BUF) do {                                             \
        _Pragma("unroll")                                                     \
        for (int i_ = 0; i_ < 4; ++i_) {                                      \
            int row_ = srow + i_;                                             \
            int fK_ = (row_ & 7) ^ ((row_ >> 3) & 7);                         \
            uint2v w_;                                                        \
            w_.x = cvtpk(stg[i_][0], stg[i_][1]);                             \
            w_.y = cvtpk(stg[i_][2], stg[i_][3]);                             \
            *(uint2v*)&Ksh[BUF][row_ * D_DIM + (scol ^ (fK_ << 3))] = w_;     \
        }                                                                     \
        _Pragma("unroll")                                                     \
        for (int j_ = 0; j_ < 4; ++j_) {                                      \
            int d_ = scol + j_;                                               \
            int g_ = (d_ & 7) ^ ((d_ >> 3) & 7);                              \
            uint2v w_;                                                        \
            w_.x = cvtpk(stg[0][j_], stg[1][j_]);                             \
            w_.y = cvtpk(stg[2][j_], stg[3][j_]);                             \
            *(uint2v*)&Vsh[BUF][d_ * KVBLK + (srow ^ (g_ << 3))] = w_;        \
        }                                                                     \
    } while (0)

    // prologue: tile 0 into buf 0
    STAGE_LOAD(0);
    STAGE_WRITE(0);
    __syncthreads();

    for (int kt = 0; kt < NKV; ++kt) {
        const int cur = kt & 1;
        // issue next tile's global loads early; written to buf cur^1 below
        if (kt + 1 < NKV) STAGE_LOAD(kt + 1);

        // ---- swapped QK^T: S^T = K_tile @ Q^T, one kf read -> 2 MFMAs ----
        f32x4 st[2][4];
        #pragma unroll
        for (int t = 0; t < 2; ++t)
            #pragma unroll
            for (int m = 0; m < 4; ++m) st[t][m] = (f32x4){0.f, 0.f, 0.f, 0.f};
        __builtin_amdgcn_s_setprio(1);
        #pragma unroll
        for (int m = 0; m < 4; ++m) {
            int row = m * 16 + lo;
            int fK = (row & 7) ^ ((row >> 3) & 7);
            #pragma unroll
            for (int kc = 0; kc < 4; ++kc) {
                f16x8 kf = *(const f16x8*)&Ksh[cur][row * D_DIM + ((kc * 32 + hi * 8) ^ (fK << 3))];
                st[0][m] = __builtin_amdgcn_mfma_f32_16x16x32_f16(kf, qf[0][kc], st[0][m], 0, 0, 0);
                st[1][m] = __builtin_amdgcn_mfma_f32_16x16x32_f16(kf, qf[1][kc], st[1][m], 0, 0, 0);
            }
        }
        __builtin_amdgcn_s_setprio(0);
        // lane holds S^T·log2e [kv = m*16 + hi*4 + r][q = wv*32 + t*16 + lo]

        // ---- softmax (permlane reductions, exp2) + in-register P re-layout ----
        f16x8 pf[2][2];
        #pragma unroll
        for (int t = 0; t < 2; ++t) {
            float tmax = -1e30f;
            #pragma unroll
            for (int m = 0; m < 4; ++m)
                #pragma unroll
                for (int r = 0; r < 4; ++r) tmax = fmaxf(tmax, st[t][m][r]);
            tmax = hired_max(tmax);

            bool skip = __all(tmax - mr[t] <= 11.5415603f);   // 8*log2e
            float mnew = skip ? mr[t] : fmaxf(mr[t], tmax);

            float ls = 0.f;
            #pragma unroll
            for (int m = 0; m < 4; ++m) {
                #pragma unroll
                for (int r = 0; r < 4; ++r) {
                    float p = EXP2(st[t][m][r] - mnew);
                    st[t][m][r] = p;
                    ls += p;
                }
            }
            ls = hired_sum(ls);

            if (!skip) {
                float scale = EXP2(mr[t] - mnew);
                lr[t] = lr[t] * scale + ls;
                float sc4[4];
                #pragma unroll
                for (int r = 0; r < 4; ++r) sc4[r] = __shfl(scale, hi * 4 + r, 64);
                #pragma unroll
                for (int n = 0; n < 8; ++n)
                    #pragma unroll
                    for (int r = 0; r < 4; ++r) oacc[t][n][r] *= sc4[r];
                mr[t] = mnew;
            } else {
                lr[t] += ls;
            }

            // pack P to fp16 pairs, then 4-op permlane network -> PV A-fragment
            unsigned cc[4][2];
            #pragma unroll
            for (int m = 0; m < 4; ++m) {
                cc[m][0] = cvtpk(st[t][m][0], st[t][m][1]);
                cc[m][1] = cvtpk(st[t][m][2], st[t][m][3]);
            }
            #pragma unroll
            for (int kc2 = 0; kc2 < 2; ++kc2) {
                unsigned r0 = cc[2 * kc2][0], r1 = cc[2 * kc2][1];
                unsigned r2 = cc[2 * kc2 + 1][0], r3 = cc[2 * kc2 + 1][1];
                uint2v s02 = __builtin_amdgcn_permlane32_swap(r0, r2, false, false);
                uint2v s13 = __builtin_amdgcn_permlane32_swap(r1, r3, false, false);
                uint2v t02 = __builtin_amdgcn_permlane16_swap(s02.x, s02.y, false, false);
                uint2v t13 = __builtin_amdgcn_permlane16_swap(s13.x, s13.y, false, false);
                union { unsigned u[4]; f16x8 v; } pu;
                pu.u[0] = t02.x; pu.u[1] = t13.x; pu.u[2] = t02.y; pu.u[3] = t13.y;
                pf[t][kc2] = pu.v;
            }
        }

        // ---- PV: O += P @ V, pf in registers, one vf read -> 2 MFMAs ----
        __builtin_amdgcn_s_setprio(1);
        #pragma unroll
        for (int kc2 = 0; kc2 < 2; ++kc2) {
            #pragma unroll
            for (int n = 0; n < 8; ++n) {
                int d = n * 16 + lo;
                int g = (d & 7) ^ ((d >> 3) & 7);
                f16x8 vf = *(const f16x8*)&Vsh[cur][d * KVBLK + ((kc2 * 32 + hi * 8) ^ (g << 3))];
                oacc[0][n] = __builtin_amdgcn_mfma_f32_16x16x32_f16(pf[0][kc2], vf, oacc[0][n], 0, 0, 0);
                oacc[1][n] = __builtin_amdgcn_mfma_f32_16x16x32_f16(pf[1][kc2], vf, oacc[1][n], 0, 0, 0);
            }
        }
        __builtin_amdgcn_s_setprio(0);

        // ---- write next tile into the other buffer; ONE barrier per tile ----
        if (kt + 1 < NKV) STAGE_WRITE(cur ^ 1);
        __syncthreads();
    }

    // ---- epilogue: O / l, write fp32 ----
    #pragma unroll
    for (int t = 0; t < 2; ++t) {
        float inv = 1.0f / lr[t];   // valid at lane's q = lo
        float rl[4];
        #pragma unroll
        for (int r = 0; r < 4; ++r) rl[r] = __shfl(inv, hi * 4 + r, 64);
        #pragma unroll
        for (int n = 0; n < 8; ++n)
            #pragma unroll
            for (int r = 0; r < 4; ++r)
                Oh[(wv * 32 + t * 16 + hi * 4 + r) * D_DIM + n * 16 + lo] = oacc[t][n][r] * rl[r];
    }
}

extern "C" void kernel_launch(void* const* d_in, const int* in_sizes, int n_in,
                              void* d_out, int out_size, void* d_ws, size_t ws_size,
                              hipStream_t stream) {
    const float* x2 = (const float*)d_in[0];
    const float* x3 = (const float*)d_in[1];
    float* out = (float*)d_out;
    dim3 grid(512), block(512);
    hipLaunchKernelGGL(attn_kernel, grid, block, 0, stream, x2, x3, out);
}

// Round 19
// 162.489 us; speedup vs baseline: 1.1017x; 1.1017x over previous
//
#include <hip/hip_runtime.h>
#include <hip/hip_bf16.h>

typedef __attribute__((ext_vector_type(4))) float f32x4;
typedef _Float16 f16;
typedef __attribute__((ext_vector_type(8))) _Float16 f16x8;
typedef __attribute__((ext_vector_type(2))) __fp16 pk16x2;       // cvt_pkrtz native return
typedef __attribute__((ext_vector_type(2))) unsigned int uint2v; // permlane*_swap return / 8B store

#define S_LEN 2048
#define D_DIM 128
#define QBLK 128
#define KVBLK 64
#define NKV (S_LEN / KVBLK)
#define LOG2E 1.44269504088896340736f
#define EXP2(x) __builtin_amdgcn_exp2f(x)   // raw v_exp_f32 (log2 domain)

__device__ __forceinline__ unsigned cvtpk(float a, float b) {
    union { pk16x2 p; unsigned u; } v;
    v.p = __builtin_amdgcn_cvt_pkrtz(a, b);
    return v.u;
}

// max over the 4 hi-groups (lanes sharing lo) via permlane swaps (VALU).
__device__ __forceinline__ float hired_max(float x) {
    uint2v s = __builtin_amdgcn_permlane16_swap(__float_as_uint(x), __float_as_uint(x), false, false);
    float m = fmaxf(__uint_as_float(s.x), __uint_as_float(s.y));
    uint2v s2 = __builtin_amdgcn_permlane32_swap(__float_as_uint(m), __float_as_uint(m), false, false);
    return fmaxf(__uint_as_float(s2.x), __uint_as_float(s2.y));
}

// softmax(x2 @ x3^T) @ x3 ; Q = x2, K = V = x3, no scale. fp16 MFMA path.
// Round-15 structure (4 waves x 32 q, (256,2) — REGISTER RULE: any tighter
// bound spills, r6/9/14/16) + VALU-count cuts (r15 regime is issue-bound:
// VALU 44% > MFMA 30%, occupancy reg-pinned at 2 waves/SIMD):
//  - softmax SUM moved to the MFMA pipe: l[q] = P . ones via 2 extra MFMAs
//    per subtile into lacc (laid out like an O column) -> deletes 32 adds +
//    hired_sum permlanes per subtile + all epilogue shfls; rescale law for
//    l is identical to O's so the !skip path covers it.
//  - max reduction written as nested triples -> v_max3_f32 fusion.
__global__ __launch_bounds__(256, 2) void attn_kernel(
    const float* __restrict__ Q, const float* __restrict__ KV,
    float* __restrict__ Out)
{
    // XCD-aware swizzle: 1024 blocks % 8 == 0 -> bijective chunked map.
    unsigned b = blockIdx.x;
    unsigned cpx = gridDim.x >> 3;               // 128
    unsigned work = (b & 7u) * cpx + (b >> 3);
    unsigned head = work >> 4;                   // 64 heads
    unsigned qt = work & 15u;                    // 16 q-tiles per head

    const float* Qh = Q + (size_t)head * (S_LEN * D_DIM) + (size_t)qt * QBLK * D_DIM;
    const float* Kh = KV + (size_t)head * (S_LEN * D_DIM);
    float* Oh = Out + (size_t)head * (S_LEN * D_DIM) + (size_t)qt * QBLK * D_DIM;

    const int tid = threadIdx.x;
    const int wv = tid >> 6;        // 0..3
    const int lane = tid & 63;
    const int lo = lane & 15;
    const int hi = lane >> 4;

    // 16 + 16 = 32 KB
    __shared__ __align__(16) f16 Ksh[KVBLK * D_DIM];      // [kv][d], swizzled
    __shared__ __align__(16) f16 Vsh[D_DIM * KVBLK];      // [d][kv] transposed, swizzled

    // staging map: thread owns 8 rows x 4 cols (rows srow.., cols scol..)
    const int srow = (tid >> 5) * 8;   // 0,8,..56
    const int scol = (tid & 31) * 4;   // 0,4,..124

    // constant ones B-fragment (fp16 1.0 x8) for the l-sum MFMA
    union { unsigned u[4]; f16x8 v; } onesu;
    onesu.u[0] = 0x3C003C00u; onesu.u[1] = 0x3C003C00u;
    onesu.u[2] = 0x3C003C00u; onesu.u[3] = 0x3C003C00u;
    const f16x8 onesf = onesu.v;

    // ---- Q fragments x log2e: Q[wv*32 + t*16 + lo][kc*32 + hi*8 + j] ----
    f16x8 qf[2][4];
    #pragma unroll
    for (int t = 0; t < 2; ++t) {
        const float* qr = Qh + (wv * 32 + t * 16 + lo) * D_DIM + hi * 8;
        #pragma unroll
        for (int kc = 0; kc < 4; ++kc) {
            f32x4 a = *(const f32x4*)(qr + kc * 32);
            f32x4 c = *(const f32x4*)(qr + kc * 32 + 4);
            union { unsigned u[4]; f16x8 v; } q;
            q.u[0] = cvtpk(a[0] * LOG2E, a[1] * LOG2E);
            q.u[1] = cvtpk(a[2] * LOG2E, a[3] * LOG2E);
            q.u[2] = cvtpk(c[0] * LOG2E, c[1] * LOG2E);
            q.u[3] = cvtpk(c[2] * LOG2E, c[3] * LOG2E);
            qf[t][kc] = q.v;
        }
    }

    f32x4 oacc[2][8];
    f32x4 lacc[2];               // l[q=hi*4+r] replicated over lo (O-column layout)
    #pragma unroll
    for (int t = 0; t < 2; ++t) {
        #pragma unroll
        for (int n = 0; n < 8; ++n) oacc[t][n] = (f32x4){0.f, 0.f, 0.f, 0.f};
        lacc[t] = (f32x4){0.f, 0.f, 0.f, 0.f};
    }
    float mr[2] = {-1e30f, -1e30f};   // log2-domain running max (valid at q=lo)

    f32x4 stg[8];

    #define STAGE_LOAD(KT) do {                                               \
        const float* p_ = Kh + (size_t)(KT) * KVBLK * D_DIM + (size_t)srow * D_DIM + scol; \
        _Pragma("unroll")                                                     \
        for (int i_ = 0; i_ < 8; ++i_) stg[i_] = *(const f32x4*)(p_ + i_ * D_DIM); \
    } while (0)

    #define STAGE_WRITE() do {                                                \
        _Pragma("unroll")                                                     \
        for (int i_ = 0; i_ < 8; ++i_) {                                      \
            int row_ = srow + i_;                                             \
            int fK_ = (row_ & 7) ^ ((row_ >> 3) & 7);                         \
            uint2v w_;                                                        \
            w_.x = cvtpk(stg[i_][0], stg[i_][1]);                             \
            w_.y = cvtpk(stg[i_][2], stg[i_][3]);                             \
            *(uint2v*)&Ksh[row_ * D_DIM + (scol ^ (fK_ << 3))] = w_;          \
        }                                                                     \
        _Pragma("unroll")                                                     \
        for (int j_ = 0; j_ < 4; ++j_) {                                      \
            int d_ = scol + j_;                                               \
            int g_ = (d_ & 7) ^ ((d_ >> 3) & 7);                              \
            union { unsigned u[4]; f16x8 v; } w_;                             \
            w_.u[0] = cvtpk(stg[0][j_], stg[1][j_]);                          \
            w_.u[1] = cvtpk(stg[2][j_], stg[3][j_]);                          \
            w_.u[2] = cvtpk(stg[4][j_], stg[5][j_]);                          \
            w_.u[3] = cvtpk(stg[6][j_], stg[7][j_]);                          \
            *(f16x8*)&Vsh[d_ * KVBLK + (srow ^ (g_ << 3))] = w_.v;            \
        }                                                                     \
    } while (0)

    // prologue: tile 0
    STAGE_LOAD(0);
    STAGE_WRITE();
    __syncthreads();

    for (int kt = 0; kt < NKV; ++kt) {
        // issue next tile's global loads early; consumed after the barrier
        if (kt + 1 < NKV) STAGE_LOAD(kt + 1);

        // ---- swapped QK^T: S^T = K_tile @ Q^T, one kf read -> 2 MFMAs ----
        f32x4 st[2][4];
        #pragma unroll
        for (int t = 0; t < 2; ++t)
            #pragma unroll
            for (int m = 0; m < 4; ++m) st[t][m] = (f32x4){0.f, 0.f, 0.f, 0.f};
        __builtin_amdgcn_s_setprio(1);
        #pragma unroll
        for (int m = 0; m < 4; ++m) {
            int row = m * 16 + lo;
            int fK = (row & 7) ^ ((row >> 3) & 7);
            #pragma unroll
            for (int kc = 0; kc < 4; ++kc) {
                f16x8 kf = *(const f16x8*)&Ksh[row * D_DIM + ((kc * 32 + hi * 8) ^ (fK << 3))];
                st[0][m] = __builtin_amdgcn_mfma_f32_16x16x32_f16(kf, qf[0][kc], st[0][m], 0, 0, 0);
                st[1][m] = __builtin_amdgcn_mfma_f32_16x16x32_f16(kf, qf[1][kc], st[1][m], 0, 0, 0);
            }
        }
        __builtin_amdgcn_s_setprio(0);
        // lane holds S^T·log2e [kv = m*16 + hi*4 + r][q = wv*32 + t*16 + lo]

        // ---- softmax (max-only reduction, exp2) + in-register P re-layout ----
        f16x8 pf[2][2];
        #pragma unroll
        for (int t = 0; t < 2; ++t) {
            // nested triples -> v_max3_f32 fusion
            float a0 = fmaxf(fmaxf(st[t][0][0], st[t][0][1]), st[t][0][2]);
            float a1 = fmaxf(fmaxf(st[t][0][3], st[t][1][0]), st[t][1][1]);
            float a2 = fmaxf(fmaxf(st[t][1][2], st[t][1][3]), st[t][2][0]);
            float a3 = fmaxf(fmaxf(st[t][2][1], st[t][2][2]), st[t][2][3]);
            float a4 = fmaxf(fmaxf(st[t][3][0], st[t][3][1]), st[t][3][2]);
            float b0 = fmaxf(fmaxf(a0, a1), a2);
            float b1 = fmaxf(fmaxf(a3, a4), st[t][3][3]);
            float tmax = hired_max(fmaxf(b0, b1));

            bool skip = __all(tmax - mr[t] <= 11.5415603f);   // 8*log2e
            float mnew = skip ? mr[t] : fmaxf(mr[t], tmax);

            #pragma unroll
            for (int m = 0; m < 4; ++m) {
                st[t][m][0] = EXP2(st[t][m][0] - mnew);
                st[t][m][1] = EXP2(st[t][m][1] - mnew);
                st[t][m][2] = EXP2(st[t][m][2] - mnew);
                st[t][m][3] = EXP2(st[t][m][3] - mnew);
            }

            if (!skip) {
                float scale = EXP2(mr[t] - mnew);
                float sc4[4];
                #pragma unroll
                for (int r = 0; r < 4; ++r) sc4[r] = __shfl(scale, hi * 4 + r, 64);
                #pragma unroll
                for (int n = 0; n < 8; ++n)
                    #pragma unroll
                    for (int r = 0; r < 4; ++r) oacc[t][n][r] *= sc4[r];
                #pragma unroll
                for (int r = 0; r < 4; ++r) lacc[t][r] *= sc4[r];
                mr[t] = mnew;
            }

            // pack P to fp16 pairs, then 4-op permlane network -> PV A-fragment
            unsigned cc[4][2];
            #pragma unroll
            for (int m = 0; m < 4; ++m) {
                cc[m][0] = cvtpk(st[t][m][0], st[t][m][1]);
                cc[m][1] = cvtpk(st[t][m][2], st[t][m][3]);
            }
            #pragma unroll
            for (int kc2 = 0; kc2 < 2; ++kc2) {
                unsigned r0 = cc[2 * kc2][0], r1 = cc[2 * kc2][1];
                unsigned r2 = cc[2 * kc2 + 1][0], r3 = cc[2 * kc2 + 1][1];
                uint2v s02 = __builtin_amdgcn_permlane32_swap(r0, r2, false, false);
                uint2v s13 = __builtin_amdgcn_permlane32_swap(r1, r3, false, false);
                uint2v t02 = __builtin_amdgcn_permlane16_swap(s02.x, s02.y, false, false);
                uint2v t13 = __builtin_amdgcn_permlane16_swap(s13.x, s13.y, false, false);
                union { unsigned u[4]; f16x8 v; } pu;
                pu.u[0] = t02.x; pu.u[1] = t13.x; pu.u[2] = t02.y; pu.u[3] = t13.y;
                pf[t][kc2] = pu.v;
            }
        }

        // ---- PV: O += P @ V (+ l += P @ 1 on the MFMA pipe) ----
        __builtin_amdgcn_s_setprio(1);
        #pragma unroll
        for (int kc2 = 0; kc2 < 2; ++kc2) {
            lacc[0] = __builtin_amdgcn_mfma_f32_16x16x32_f16(pf[0][kc2], onesf, lacc[0], 0, 0, 0);
            lacc[1] = __builtin_amdgcn_mfma_f32_16x16x32_f16(pf[1][kc2], onesf, lacc[1], 0, 0, 0);
            #pragma unroll
            for (int n = 0; n < 8; ++n) {
                int d = n * 16 + lo;
                int g = (d & 7) ^ ((d >> 3) & 7);
                f16x8 vf = *(const f16x8*)&Vsh[d * KVBLK + ((kc2 * 32 + hi * 8) ^ (g << 3))];
                oacc[0][n] = __builtin_amdgcn_mfma_f32_16x16x32_f16(pf[0][kc2], vf, oacc[0][n], 0, 0, 0);
                oacc[1][n] = __builtin_amdgcn_mfma_f32_16x16x32_f16(pf[1][kc2], vf, oacc[1][n], 0, 0, 0);
            }
        }
        __builtin_amdgcn_s_setprio(0);

        __syncthreads();                    // all waves done reading Ksh/Vsh
        if (kt + 1 < NKV) {
            STAGE_WRITE();                  // overwrite with next tile
            __syncthreads();                // next tile visible to all
        }
    }

    // ---- epilogue: O / l (l already in output layout; no shfls) ----
    #pragma unroll
    for (int t = 0; t < 2; ++t) {
        float rl[4];
        #pragma unroll
        for (int r = 0; r < 4; ++r) rl[r] = 1.0f / lacc[t][r];
        #pragma unroll
        for (int n = 0; n < 8; ++n)
            #pragma unroll
            for (int r = 0; r < 4; ++r)
                Oh[(wv * 32 + t * 16 + hi * 4 + r) * D_DIM + n * 16 + lo] = oacc[t][n][r] * rl[r];
    }
}

extern "C" void kernel_launch(void* const* d_in, const int* in_sizes, int n_in,
                              void* d_out, int out_size, void* d_ws, size_t ws_size,
                              hipStream_t stream) {
    const float* x2 = (const float*)d_in[0];
    const float* x3 = (const float*)d_in[1];
    float* out = (float*)d_out;
    dim3 grid(1024), block(256);
    hipLaunchKernelGGL(attn_kernel, grid, block, 0, stream, x2, x3, out);
}